// Round 10
// baseline (740.495 us; speedup 1.0000x reference)
//
#include <hip/hip_runtime.h>
#include <hip/hip_cooperative_groups.h>
#include <math.h>

namespace cg = cooperative_groups;

// ---------------------------------------------------------------------------
// GCTLN round 10: multiple-shooting scan, de-risked cooperative mega-kernel.
//   k_coarse : serial fp32 RK4, dt=0.45 (2224 steps)  [unchanged]
//   k_mega   : coop, 245 blocks x 256 thr (co-resident at ANY VGPR count).
//              Each thread owns FCH=16 steps. Per iteration: walk-and-build
//              (exact fp32 dopri5 steps, recording affine maps) -> wave/block
//              scan -> grid.sync -> block0 scans 245 totals -> grid.sync ->
//              fold -> new group-start state. 4 iterations. Writes gstart.
//   k_polish : fp64 exact re-integration of each group from gstart,
//              readout fused.
//   Fallback : if coop launch errors, identical math via split kernels.
// ---------------------------------------------------------------------------

#define C21 (1.0/5.0)
#define C31 (3.0/40.0)
#define C32 (9.0/40.0)
#define C41 (44.0/45.0)
#define C42 (-56.0/15.0)
#define C43 (32.0/9.0)
#define C51 (19372.0/6561.0)
#define C52 (-25360.0/2187.0)
#define C53 (64448.0/6561.0)
#define C54 (-212.0/729.0)
#define C61 (9017.0/3168.0)
#define C62 (-355.0/33.0)
#define C63 (46732.0/5247.0)
#define C64 (49.0/176.0)
#define C65 (-5103.0/18656.0)
#define B1  (35.0/384.0)
#define B3  (500.0/1113.0)
#define B4  (125.0/192.0)
#define B5  (-2187.0/6784.0)
#define B6  (11.0/84.0)

#define FT 256       // threads per block
#define FT_LOG2 8
#define FCH 16       // steps per thread (group)
#define NITER 4

struct MapF { float A[9]; float b[3]; };

__device__ inline void map_identity(MapF& m) {
#pragma unroll
  for (int i = 0; i < 9; ++i) m.A[i] = 0.f;
  m.A[0] = m.A[4] = m.A[8] = 1.f;
  m.b[0] = m.b[1] = m.b[2] = 0.f;
}

// out = m2 ∘ m1 (m1 applied first). out must not alias inputs.
__device__ inline void map_compose(MapF& out, const MapF& m2, const MapF& m1) {
#pragma unroll
  for (int r = 0; r < 3; ++r) {
#pragma unroll
    for (int c = 0; c < 3; ++c)
      out.A[r*3+c] = m2.A[r*3+0]*m1.A[0+c] + m2.A[r*3+1]*m1.A[3+c] + m2.A[r*3+2]*m1.A[6+c];
    out.b[r] = m2.A[r*3+0]*m1.b[0] + m2.A[r*3+1]*m1.b[1] + m2.A[r*3+2]*m1.b[2] + m2.b[r];
  }
}

__device__ inline void map_apply(const MapF& m, const float x[3], float y[3]) {
#pragma unroll
  for (int r = 0; r < 3; ++r)
    y[r] = m.A[r*3+0]*x[0] + m.A[r*3+1]*x[1] + m.A[r*3+2]*x[2] + m.b[r];
}

__device__ inline MapF map_shfl_up(const MapF& m, int off) {
  MapF r;
#pragma unroll
  for (int i = 0; i < 9; ++i) r.A[i] = __shfl_up(m.A[i], off, 64);
#pragma unroll
  for (int i = 0; i < 3; ++i) r.b[i] = __shfl_up(m.b[i], off, 64);
  return r;
}

template <typename T, bool RECORD>
__device__ inline void stage_k(const T z[3], const T th[3],
                               T wa, T wb, T g[3], T k[3]) {
  T y0 = fma(wa, z[2], fma(wb, z[1], th[0]));
  T y1 = fma(wa, z[0], fma(wb, z[2], th[1]));
  T y2 = fma(wa, z[1], fma(wb, z[0], th[2]));
  if (RECORD) {
    g[0] = (y0 > T(0)) ? T(1) : T(0);
    g[1] = (y1 > T(0)) ? T(1) : T(0);
    g[2] = (y2 > T(0)) ? T(1) : T(0);
  }
  k[0] = y0 * g[0] - z[0];
  k[1] = y1 * g[1] - z[1];
  k[2] = y2 * g[2] - z[2];
}

// RECORD=true: exact dopri5 step (gates from actual stage values).
template <typename T, bool RECORD>
__device__ inline void dopri_eval(const T v[3], const T th[3], T dt,
                                  T wa, T wb, T G[6][3], T out[3]) {
  T k1[3], k2[3], k3[3], k4[3], k5[3], k6[3], z[3];
  stage_k<T, RECORD>(v, th, wa, wb, G[0], k1);
  const T d21 = dt * T(C21);
#pragma unroll
  for (int c = 0; c < 3; ++c) z[c] = fma(d21, k1[c], v[c]);
  stage_k<T, RECORD>(z, th, wa, wb, G[1], k2);
#pragma unroll
  for (int c = 0; c < 3; ++c) z[c] = fma(dt, fma(T(C31), k1[c], T(C32) * k2[c]), v[c]);
  stage_k<T, RECORD>(z, th, wa, wb, G[2], k3);
#pragma unroll
  for (int c = 0; c < 3; ++c)
    z[c] = fma(dt, fma(T(C41), k1[c], fma(T(C42), k2[c], T(C43) * k3[c])), v[c]);
  stage_k<T, RECORD>(z, th, wa, wb, G[3], k4);
#pragma unroll
  for (int c = 0; c < 3; ++c)
    z[c] = fma(dt, fma(T(C51), k1[c], fma(T(C52), k2[c], fma(T(C53), k3[c], T(C54) * k4[c]))), v[c]);
  stage_k<T, RECORD>(z, th, wa, wb, G[4], k5);
#pragma unroll
  for (int c = 0; c < 3; ++c)
    z[c] = fma(dt, fma(T(C61), k1[c], fma(T(C62), k2[c], fma(T(C63), k3[c], fma(T(C64), k4[c], T(C65) * k5[c])))), v[c]);
  stage_k<T, RECORD>(z, th, wa, wb, G[5], k6);
#pragma unroll
  for (int c = 0; c < 3; ++c)
    out[c] = fma(dt, fma(T(B1), k1[c], fma(T(B3), k3[c], fma(T(B4), k4[c], fma(T(B5), k5[c], T(B6) * k6[c])))), v[c]);
}

// Build step map at x AND advance x by the exact nonlinear step.
__device__ inline void build_map_step(float x[3], float dt, float wa, float wb,
                                      const float th[3], MapF& m) {
  float G[6][3], xn[3];
  dopri_eval<float, true>(x, th, dt, wa, wb, G, xn);   // exact step + gates
  const float z3[3] = {0.f, 0.f, 0.f};
  dopri_eval<float, false>(z3, th, dt, wa, wb, G, m.b);  // b = F(0)
  float e[3], col[3];
#pragma unroll
  for (int j = 0; j < 3; ++j) {
    e[0] = 0.f; e[1] = 0.f; e[2] = 0.f; e[j] = 1.f;
    dopri_eval<float, false>(e, z3, dt, wa, wb, G, col); // A e_j (theta = 0)
    m.A[0 + j] = col[0];
    m.A[3 + j] = col[1];
    m.A[6 + j] = col[2];
  }
  x[0] = xn[0]; x[1] = xn[1]; x[2] = xn[2];
}

// In-block exclusive scan. Input: run = this thread's element. Output:
// P = exclusive prefix, tot = inclusive prefix. Uses wtot (>= FT/64 entries).
__device__ inline void block_scan(MapF run, MapF& P, MapF& tot,
                                  MapF* wtot, int lane, int wid) {
#pragma unroll
  for (int off = 1; off < 64; off <<= 1) {
    MapF nb = map_shfl_up(run, off);
    MapF c; map_compose(c, run, nb);
    if (lane >= off) run = c;
  }
  __syncthreads();                 // protect wtot vs previous use
  if (lane == 63) wtot[wid] = run;
  __syncthreads();
  MapF wpre; map_identity(wpre);
  for (int w = 0; w < wid; ++w) { MapF t2; map_compose(t2, wtot[w], wpre); wpre = t2; }
  MapF excl = map_shfl_up(run, 1);
  if (lane == 0) map_identity(excl);
  map_compose(P, excl, wpre);
  map_compose(tot, run, wpre);
}

// walk-and-build a group's total map from start xs (exact fp32 shooting)
__device__ inline void group_walk(float xs[3], const float dtg[FCH],
                                  float wa, float wb, const float th[3],
                                  MapF& run) {
  map_identity(run);
  MapF mp, tmp;
  float x[3] = {xs[0], xs[1], xs[2]};
#pragma unroll
  for (int s = 0; s < FCH; ++s) {
    build_map_step(x, dtg[s], wa, wb, th, mp);
    map_compose(tmp, mp, run);
    run = tmp;
  }
}

// load per-thread dts (clamped; padding steps get dt=0 -> identity maps)
__device__ inline void load_dtg(const float* __restrict__ t_eval, int n0, int T,
                                float dtg[FCH], float& tv0) {
  int i0 = n0 > T - 1 ? T - 1 : n0;
  tv0 = t_eval[i0];
  float prev = tv0;
#pragma unroll
  for (int s = 1; s <= FCH; ++s) {
    int idx = n0 + s; if (idx > T - 1) idx = T - 1;
    float c = t_eval[idx];
    dtg[s - 1] = c - prev;
    prev = c;
  }
}

// ----------------------------- kernels -------------------------------------

// sequential fp32 RK4 seed at fixed dtc (mask-guess quality only)
__global__ void k_coarse(const float* __restrict__ x0f,
                         const float* __restrict__ le, const float* __restrict__ ld,
                         const float* __restrict__ thf,
                         float* __restrict__ cst, int NC, float dtc) {
  if (threadIdx.x != 0 || blockIdx.x != 0) return;
  const float a = -1.f + expf(le[0]);
  const float b = -1.f - expf(ld[0]);
  const float t0 = thf[0], t1 = thf[1], t2 = thf[2];
  float x = x0f[0], y = x0f[1], z = x0f[2];
  cst[0] = x; cst[1] = y; cst[2] = z;
  const float dt = dtc, dth = 0.5f * dtc, dt6 = dtc * (1.f / 6.f);
#define RHSF(px, py, pz, kx, ky, kz)                      \
  do {                                                    \
    float y0_ = fmaf(a, (pz), fmaf(b, (py), t0));         \
    float y1_ = fmaf(a, (px), fmaf(b, (pz), t1));         \
    float y2_ = fmaf(a, (py), fmaf(b, (px), t2));         \
    (kx) = fmaxf(y0_, 0.f) - (px);                        \
    (ky) = fmaxf(y1_, 0.f) - (py);                        \
    (kz) = fmaxf(y2_, 0.f) - (pz);                        \
  } while (0)
  for (int i = 1; i <= NC; ++i) {
    float k1x,k1y,k1z,k2x,k2y,k2z,k3x,k3y,k3z,k4x,k4y,k4z,zx,zy,zz;
    RHSF(x, y, z, k1x, k1y, k1z);
    zx = fmaf(dth, k1x, x); zy = fmaf(dth, k1y, y); zz = fmaf(dth, k1z, z);
    RHSF(zx, zy, zz, k2x, k2y, k2z);
    zx = fmaf(dth, k2x, x); zy = fmaf(dth, k2y, y); zz = fmaf(dth, k2z, z);
    RHSF(zx, zy, zz, k3x, k3y, k3z);
    zx = fmaf(dt, k3x, x); zy = fmaf(dt, k3y, y); zz = fmaf(dt, k3z, z);
    RHSF(zx, zy, zz, k4x, k4y, k4z);
    x = fmaf(dt6, k1x + 2.f*k2x + 2.f*k3x + k4x, x);
    y = fmaf(dt6, k1y + 2.f*k2y + 2.f*k3y + k4y, y);
    z = fmaf(dt6, k1z + 2.f*k2z + 2.f*k3z + k4z, z);
    cst[3*i] = x; cst[3*i+1] = y; cst[3*i+2] = z;
  }
#undef RHSF
}

// -------- cooperative mega kernel (245 blocks: always co-resident) ---------
__global__ __launch_bounds__(FT) void k_mega(
    const float* __restrict__ t_eval, const float* __restrict__ seedst,
    const float* __restrict__ x0f,
    const float* __restrict__ le, const float* __restrict__ ld,
    const float* __restrict__ thf,
    float* __restrict__ gstart,
    MapF* __restrict__ btot, MapF* __restrict__ bpre,
    int S, int T, int NG1, int NB, float hseed, int nstates) {
  cg::grid_group grid = cg::this_grid();
  __shared__ MapF wtot[FT / 64];

  const int t = threadIdx.x;
  const int lane = t & 63, wid = t >> 6;
  const int g = blockIdx.x * FT + t;
  const bool active = (g < NG1);
  const int n0 = g * FCH;

  const float wa = -1.f + expf(le[0]);
  const float wb = -1.f - expf(ld[0]);
  const float th[3] = {thf[0], thf[1], thf[2]};
  const float x0d[3] = {x0f[0], x0f[1], x0f[2]};

  float dtg[FCH];
  float xs[3] = {0.f, 0.f, 0.f};
  if (active) {
    float tv0;
    load_dtg(t_eval, n0, T, dtg, tv0);
    float u = tv0 / hseed;
    int j = (int)u;
    if (j < 0) j = 0;
    if (j > nstates - 2) j = nstates - 2;
    float f = u - (float)j;
#pragma unroll
    for (int c = 0; c < 3; ++c) {
      float a0 = seedst[3*j + c], b0 = seedst[3*(j+1) + c];
      xs[c] = a0 + f * (b0 - a0);
    }
  } else {
#pragma unroll
    for (int s = 0; s < FCH; ++s) dtg[s] = 0.f;
  }
  if (g == 0) { xs[0] = x0d[0]; xs[1] = x0d[1]; xs[2] = x0d[2]; }

  for (int it = 0; it < NITER; ++it) {
    MapF run;
    if (active) group_walk(xs, dtg, wa, wb, th, run);
    else map_identity(run);

    MapF P, tot;
    block_scan(run, P, tot, wtot, lane, wid);
    if (t == FT - 1) btot[blockIdx.x] = tot;
    grid.sync();

    if (blockIdx.x == 0) {
      MapF rb;
      if (t < NB) rb = btot[t]; else map_identity(rb);
      MapF Pb, totb;
      block_scan(rb, Pb, totb, wtot, lane, wid);
      if (t < NB) bpre[t] = Pb;
    }
    grid.sync();

    {
      MapF bp = bpre[blockIdx.x];
      MapF Pn; map_compose(Pn, P, bp);
      float ns[3]; map_apply(Pn, x0d, ns);
      if (active && g != 0) { xs[0] = ns[0]; xs[1] = ns[1]; xs[2] = ns[2]; }
    }
  }

  if (active) {
    gstart[3*g]   = xs[0];
    gstart[3*g+1] = xs[1];
    gstart[3*g+2] = xs[2];
  }
}

// -------- fp64 polish + fused readout --------------------------------------
__global__ __launch_bounds__(256) void k_polish(
    const float* __restrict__ t_eval, const float* __restrict__ gstart,
    const float* __restrict__ x0f,
    const float* __restrict__ le, const float* __restrict__ ld,
    const float* __restrict__ thf,
    const float* __restrict__ row, const float* __restrict__ rob,
    float* __restrict__ traj, float* __restrict__ pred, int S, int T, int NG1) {
  const int g = blockIdx.x * blockDim.x + threadIdx.x;
  if (g >= NG1) return;
  const int n0 = g * FCH;
  float dtg[FCH]; float tv0;
  load_dtg(t_eval, n0, T, dtg, tv0);

  const double wa = -1.0 + exp((double)le[0]);
  const double wb = -1.0 - exp((double)ld[0]);
  const double th[3] = {(double)thf[0], (double)thf[1], (double)thf[2]};
  const float w00 = row[0], w01 = row[1], w02 = row[2];
  const float w10 = row[3], w11 = row[4], w12 = row[5];
  const float w20 = row[6], w21 = row[7], w22 = row[8];
  const float b0 = rob[0], b1 = rob[1], b2 = rob[2];

  double x[3];
  if (g == 0) {
    x[0] = (double)x0f[0]; x[1] = (double)x0f[1]; x[2] = (double)x0f[2];
    float a0 = x0f[0], a1 = x0f[1], a2 = x0f[2];
    traj[0] = a0; traj[1] = a1; traj[2] = a2;
    pred[0] = fmaf(w00, a0, fmaf(w01, a1, fmaf(w02, a2, b0)));
    pred[1] = fmaf(w10, a0, fmaf(w11, a1, fmaf(w12, a2, b1)));
    pred[2] = fmaf(w20, a0, fmaf(w21, a1, fmaf(w22, a2, b2)));
  } else {
    x[0] = (double)gstart[3*g]; x[1] = (double)gstart[3*g+1]; x[2] = (double)gstart[3*g+2];
  }

  double G[6][3], xn[3];
#pragma unroll
  for (int s = 0; s < FCH; ++s) {
    dopri_eval<double, true>(x, th, (double)dtg[s], wa, wb, G, xn);
    x[0] = xn[0]; x[1] = xn[1]; x[2] = xn[2];
    int n = n0 + s;
    if (n < S) {
      float a0 = (float)x[0], a1 = (float)x[1], a2 = (float)x[2];
      traj[3*(n+1)]   = a0;
      traj[3*(n+1)+1] = a1;
      traj[3*(n+1)+2] = a2;
      pred[3*(n+1)]   = fmaf(w00, a0, fmaf(w01, a1, fmaf(w02, a2, b0)));
      pred[3*(n+1)+1] = fmaf(w10, a0, fmaf(w11, a1, fmaf(w12, a2, b1)));
      pred[3*(n+1)+2] = fmaf(w20, a0, fmaf(w21, a1, fmaf(w22, a2, b2)));
    }
  }
}

// -------- fallback split kernels (same math, no grid.sync) -----------------

__global__ void k_start0(const float* __restrict__ t_eval,
                         const float* __restrict__ seedst,
                         const float* __restrict__ x0f,
                         float* __restrict__ gs, int T, int NG1,
                         float hseed, int nstates) {
  int g = blockIdx.x * blockDim.x + threadIdx.x;
  if (g >= NG1) return;
  if (g == 0) { gs[0] = x0f[0]; gs[1] = x0f[1]; gs[2] = x0f[2]; return; }
  int n0 = g * FCH; if (n0 > T - 1) n0 = T - 1;
  float u = t_eval[n0] / hseed;
  int j = (int)u;
  if (j < 0) j = 0;
  if (j > nstates - 2) j = nstates - 2;
  float f = u - (float)j;
#pragma unroll
  for (int c = 0; c < 3; ++c) {
    float a0 = seedst[3*j + c], b0 = seedst[3*(j+1) + c];
    gs[3*g + c] = a0 + f * (b0 - a0);
  }
}

__global__ __launch_bounds__(FT) void k_up_fb(
    const float* __restrict__ t_eval, const float* __restrict__ gs,
    const float* __restrict__ le, const float* __restrict__ ld,
    const float* __restrict__ thf,
    MapF* __restrict__ lpre, MapF* __restrict__ btot, int T, int NG1) {
  __shared__ MapF wtot[FT / 64];
  const int t = threadIdx.x, lane = t & 63, wid = t >> 6;
  const int g = blockIdx.x * FT + t;
  const bool active = (g < NG1);
  const float wa = -1.f + expf(le[0]);
  const float wb = -1.f - expf(ld[0]);
  const float th[3] = {thf[0], thf[1], thf[2]};
  MapF run;
  if (active) {
    float dtg[FCH]; float tv0;
    load_dtg(t_eval, g * FCH, T, dtg, tv0);
    float xs[3] = {gs[3*g], gs[3*g+1], gs[3*g+2]};
    group_walk(xs, dtg, wa, wb, th, run);
  } else map_identity(run);
  MapF P, tot;
  block_scan(run, P, tot, wtot, lane, wid);
  if (active) lpre[g] = P;
  if (t == FT - 1) btot[blockIdx.x] = tot;
}

__global__ __launch_bounds__(FT) void k_bscan_fb(const MapF* __restrict__ btot,
                                                 MapF* __restrict__ bpre, int NB) {
  __shared__ MapF wtot[FT / 64];
  const int t = threadIdx.x, lane = t & 63, wid = t >> 6;
  MapF run;
  if (t < NB) run = btot[t]; else map_identity(run);
  MapF P, tot;
  block_scan(run, P, tot, wtot, lane, wid);
  if (t < NB) bpre[t] = P;
}

__global__ void k_fold_fb(const MapF* __restrict__ lpre, const MapF* __restrict__ bpre,
                          const float* __restrict__ x0f,
                          float* __restrict__ gsout, int NG1) {
  int g = blockIdx.x * blockDim.x + threadIdx.x;
  if (g >= NG1) return;
  if (g == 0) { gsout[0] = x0f[0]; gsout[1] = x0f[1]; gsout[2] = x0f[2]; return; }
  MapF P;
  map_compose(P, lpre[g], bpre[g >> FT_LOG2]);
  float x0d[3] = {x0f[0], x0f[1], x0f[2]}, ns[3];
  map_apply(P, x0d, ns);
  gsout[3*g] = ns[0]; gsout[3*g+1] = ns[1]; gsout[3*g+2] = ns[2];
}

// ----------------------------- launcher ------------------------------------

extern "C" void kernel_launch(void* const* d_in, const int* in_sizes, int n_in,
                              void* d_out, int out_size, void* d_ws, size_t ws_size,
                              hipStream_t stream) {
  const float* t_eval    = (const float*)d_in[0];
  const float* x0        = (const float*)d_in[1];
  const float* log_eps   = (const float*)d_in[2];
  const float* log_delta = (const float*)d_in[3];
  const float* theta     = (const float*)d_in[4];
  const float* readout_w = (const float*)d_in[5];
  const float* readout_b = (const float*)d_in[6];

  int T_   = in_sizes[0];
  int S_   = T_ - 1;
  int NG1_ = (S_ + FCH - 1) / FCH;              // 62500 groups
  int NB_  = (NG1_ + FT - 1) / FT;              // 245 blocks <= 256 CUs

  const float DTS_SEED = 0.45f;
  const int   NSEED    = (int)(((double)S_ * 1e-3) / (double)DTS_SEED) + 2;  // 2224
  int nstates_ = NSEED + 1;
  float hseed_ = DTS_SEED;

  float* trajh = (float*)d_out;
  float* predh = trajh + (size_t)3 * T_;

  char* w = (char*)d_ws;
  float* seedst = (float*)w;  w += (((size_t)3 * (NSEED + 1) * 4) + 255) & ~(size_t)255;
  float* gsA    = (float*)w;  w += (((size_t)3 * NG1_ * 4) + 255) & ~(size_t)255;
  float* gsB    = (float*)w;  w += (((size_t)3 * NG1_ * 4) + 255) & ~(size_t)255;
  MapF* lpre    = (MapF*)w;   w += (((size_t)NG1_ * sizeof(MapF)) + 255) & ~(size_t)255;
  MapF* btot    = (MapF*)w;   w += (((size_t)NB_ * sizeof(MapF)) + 255) & ~(size_t)255;
  MapF* bpre    = (MapF*)w;

  k_coarse<<<1, 64, 0, stream>>>(x0, log_eps, log_delta, theta, seedst, NSEED, DTS_SEED);

  const float* t_eval_ = t_eval;
  const float* seedst_ = seedst;
  const float* x0_ = x0;
  const float* le_ = log_eps;
  const float* ld_ = log_delta;
  const float* th_ = theta;
  float* gs_ = gsA;
  MapF* btot_ = btot;
  MapF* bpre_ = bpre;

  void* args[] = {
    (void*)&t_eval_, (void*)&seedst_, (void*)&x0_, (void*)&le_, (void*)&ld_,
    (void*)&th_, (void*)&gs_, (void*)&btot_, (void*)&bpre_,
    (void*)&S_, (void*)&T_, (void*)&NG1_, (void*)&NB_,
    (void*)&hseed_, (void*)&nstates_,
  };
  hipError_t cerr = hipLaunchCooperativeKernel((const void*)k_mega, dim3(NB_), dim3(FT),
                                               args, 0, stream);
  const float* finalgs = gsA;
  if (cerr != hipSuccess) {
    // fallback: identical math via split kernels
    k_start0<<<(NG1_ + 255) / 256, 256, 0, stream>>>(t_eval, seedst, x0, gsA,
                                                     T_, NG1_, hseed_, nstates_);
    float* cur = gsA; float* nxt = gsB;
    for (int it = 0; it < NITER; ++it) {
      k_up_fb<<<NB_, FT, 0, stream>>>(t_eval, cur, log_eps, log_delta, theta,
                                      lpre, btot, T_, NG1_);
      k_bscan_fb<<<1, FT, 0, stream>>>(btot, bpre, NB_);
      k_fold_fb<<<(NG1_ + 255) / 256, 256, 0, stream>>>(lpre, bpre, x0, nxt, NG1_);
      float* tmp = cur; cur = nxt; nxt = tmp;
    }
    finalgs = cur;
  }

  k_polish<<<(NG1_ + 255) / 256, 256, 0, stream>>>(t_eval, finalgs, x0,
                                                   log_eps, log_delta, theta,
                                                   readout_w, readout_b,
                                                   trajh, predh, S_, T_, NG1_);
}